// Round 5
// baseline (771.747 us; speedup 1.0000x reference)
//
#include <hip/hip_runtime.h>
#include <hip/hip_bf16.h>
#include <math.h>

#define BATCH  2
#define SEQ    2048
#define DMODEL 256
#define DSTATE 16
#define DINNER 512
#define RTOT   4096
#define GCH    128
#define LCH    16
#define NW1    (2*DINNER*DMODEL)   // 262144
#define NW2    (DMODEL*DINNER)     // 131072

typedef float f32x4 __attribute__((ext_vector_type(4)));
typedef short s16x8 __attribute__((ext_vector_type(8)));

__device__ __forceinline__ float silu_f(float v){ return v / (1.f + __expf(-v)); }
__device__ __forceinline__ ushort f2bf(float f){
  __hip_bfloat16 h = __float2bfloat16(f);
  return *reinterpret_cast<ushort*>(&h);
}
__device__ __forceinline__ float bf2f(ushort u){
  union { unsigned int i; float f; } c; c.i = ((unsigned int)u) << 16; return c.f;
}

// ---- workspace layout (float offsets from ws base) ----
#define OFF_BC    16
#define OFF_P     (OFF_BC + RTOT*32)
#define OFF_S     (OFF_P + 2*GCH*16*512)
#define OFF_H     (OFF_S + 2*GCH*16*512)
#define OFF_ANV   (OFF_H + 2*GCH*16*512)
#define OFF_US    (OFF_ANV + 16*512)
// ushort offsets relative to ushort region
#define UOFF_HB   ((size_t)0)
#define UOFF_WIB  (UOFF_HB + (size_t)RTOT*DMODEL)
#define UOFF_WOB  (UOFF_WIB + (size_t)NW1)
#define UOFF_XZ   (UOFF_WOB + (size_t)NW2)
#define UOFF_XC   (UOFF_XZ + (size_t)RTOT*1024)
#define UOFF_G    (UOFF_XC + (size_t)RTOT*512)
#define UOFF_DL   (UOFF_G  + (size_t)RTOT*512)
#define UOFF_YG   (UOFF_DL + (size_t)RTOT*512)

// grid-wide epoch barrier: bar[0]=count, bar[1]=epoch (both zeroed per launch)
__device__ __forceinline__ void gbar(int* bar, int id){
  __syncthreads();
  if (threadIdx.x == 0) {
    __threadfence();
    int old = atomicAdd(&bar[0], 1);
    if (old == (int)gridDim.x - 1) {
      __hip_atomic_store(&bar[0], 0, __ATOMIC_RELAXED, __HIP_MEMORY_SCOPE_AGENT);
      __hip_atomic_store(&bar[1], id, __ATOMIC_RELEASE, __HIP_MEMORY_SCOPE_AGENT);
    } else {
      for (long k = 0; k < (1L << 31); ++k) {
        if (__hip_atomic_load(&bar[1], __ATOMIC_ACQUIRE, __HIP_MEMORY_SCOPE_AGENT) >= id) break;
        __builtin_amdgcn_s_sleep(4);
      }
    }
    __threadfence();
  }
  __syncthreads();
}

__global__ __launch_bounds__(256, 2) void k_mega(
    const float* __restrict__ x,
    const float* __restrict__ norm_w,
    const float* __restrict__ w_in,
    const float* __restrict__ conv_w,
    const float* __restrict__ conv_b,
    const float* __restrict__ xpw,
    const float* __restrict__ dtw,
    const float* __restrict__ dtb,
    const float* __restrict__ A_log,
    const float* __restrict__ Dw,
    const float* __restrict__ w_out,
    float* __restrict__ out,
    float* __restrict__ ws){
  __shared__ __align__(16) char smem[36864];
  int* bar = (int*)ws;
  float* BCbuf = ws + OFF_BC;
  float* Pbuf  = ws + OFF_P;
  float* Sbuf  = ws + OFF_S;
  float* Hinit = ws + OFF_H;
  float* anv   = ws + OFF_ANV;
  ushort* ub   = (ushort*)(ws + OFF_US);
  ushort* hb   = ub + UOFF_HB;
  ushort* wib  = ub + UOFF_WIB;
  ushort* wob  = ub + UOFF_WOB;
  ushort* xzb  = ub + UOFF_XZ;
  ushort* xcb  = ub + UOFF_XC;
  ushort* gb   = ub + UOFF_G;
  ushort* delt = ub + UOFF_DL;
  ushort* ygb  = ub + UOFF_YG;

  int bid = blockIdx.x;
  int t = threadIdx.x;

  // ============ phase 0: RMSNorm+transpose | weight cvt | A-table ============
  if (bid < 64) {
    ushort (*Ls)[272] = (ushort(*)[272])smem;
    float (*red)[64] = (float(*)[64])(smem + 64*272*2);
    int b = bid >> 5, l0 = (bid & 31) << 6;
    int ll = t & 63, cq = t >> 6;
    const float* xb = x + (size_t)b * DMODEL * SEQ;
    float ss = 0.f;
    for (int it = 0; it < 64; ++it) {
      int c = cq * 64 + it;
      float v = xb[(size_t)c * SEQ + l0 + ll];
      ss += v * v;
    }
    red[cq][ll] = ss;
    __syncthreads();
    float s = red[0][ll] + red[1][ll] + red[2][ll] + red[3][ll];
    float r = rsqrtf(s * (1.f / DMODEL) + 1e-5f);
    for (int it = 0; it < 64; ++it) {
      int c = cq * 64 + it;
      float v = xb[(size_t)c * SEQ + l0 + ll];
      Ls[ll][c] = f2bf(v * r * norm_w[c]);
    }
    __syncthreads();
    int row = t >> 2;
#pragma unroll
    for (int i = 0; i < 8; ++i) {
      int ch = (t & 3) + i * 4;
      int4 v = *reinterpret_cast<const int4*>(&Ls[row][ch * 8]);
      *reinterpret_cast<int4*>(&hb[((size_t)(b * SEQ + l0 + row)) * DMODEL + ch * 8]) = v;
    }
  } else if (bid < 448) {
    int base = (bid - 64) * 1024 + t * 4;
    if (base < NW1) {
      float4 v = *reinterpret_cast<const float4*>(&w_in[base]);
      ushort4 o; o.x = f2bf(v.x); o.y = f2bf(v.y); o.z = f2bf(v.z); o.w = f2bf(v.w);
      *reinterpret_cast<ushort4*>(&wib[base]) = o;
    } else {
      int j = base - NW1;
      float4 v = *reinterpret_cast<const float4*>(&w_out[j]);
      ushort4 o; o.x = f2bf(v.x); o.y = f2bf(v.y); o.z = f2bf(v.z); o.w = f2bf(v.w);
      *reinterpret_cast<ushort4*>(&wob[j]) = o;
    }
  } else if (bid < 450) {
    int d = (bid - 448) * 256 + t;
#pragma unroll
    for (int n = 0; n < 16; ++n)
      anv[n * 512 + d] = -__expf(A_log[d * 16 + n]);
  }
  gbar(bar, 1);

  // ============ phase 1: GEMM1 (bf16 MFMA) 128x64 tiles -> xzb ============
  {
    ushort (*Als)[72] = (ushort(*)[72])smem;
    ushort (*Bls)[72] = (ushort(*)[72])(smem + 128*72*2);
    int m0 = (bid >> 4) * 128, n0 = (bid & 15) * 64;
    int w = t >> 6, l = t & 63;
    int wr = w >> 1, wc = w & 1;
    f32x4 acc[4][2] = {};
    int sr = t >> 3, sc = t & 7;
    for (int k0 = 0; k0 < DMODEL; k0 += 64) {
#pragma unroll
      for (int p = 0; p < 4; ++p) {
        int r = sr + p * 32;
        *reinterpret_cast<int4*>(&Als[r][sc * 8]) =
          *reinterpret_cast<const int4*>(&hb[((size_t)(m0 + r)) * DMODEL + k0 + sc * 8]);
      }
#pragma unroll
      for (int p = 0; p < 2; ++p) {
        int r = sr + p * 32;
        *reinterpret_cast<int4*>(&Bls[r][sc * 8]) =
          *reinterpret_cast<const int4*>(&wib[((size_t)(n0 + r)) * DMODEL + k0 + sc * 8]);
      }
      __syncthreads();
#pragma unroll
      for (int ks = 0; ks < 2; ++ks) {
        s16x8 af[4], bf[2];
        int kk = ks * 32 + 8 * (l >> 4);
#pragma unroll
        for (int i = 0; i < 4; ++i)
          af[i] = *reinterpret_cast<const s16x8*>(&Als[wr * 64 + i * 16 + (l & 15)][kk]);
#pragma unroll
        for (int i = 0; i < 2; ++i)
          bf[i] = *reinterpret_cast<const s16x8*>(&Bls[wc * 32 + i * 16 + (l & 15)][kk]);
#pragma unroll
        for (int mi = 0; mi < 4; ++mi)
#pragma unroll
          for (int ni = 0; ni < 2; ++ni)
            acc[mi][ni] = __builtin_amdgcn_mfma_f32_16x16x32_bf16(af[mi], bf[ni], acc[mi][ni], 0, 0, 0);
      }
      __syncthreads();
    }
    int rq = l >> 4, cc = l & 15;
#pragma unroll
    for (int mi = 0; mi < 4; ++mi)
#pragma unroll
      for (int ni = 0; ni < 2; ++ni) {
        int n = n0 + wc * 32 + ni * 16 + cc;
        int mB = m0 + wr * 64 + mi * 16 + rq * 4;
#pragma unroll
        for (int r2 = 0; r2 < 4; ++r2)
          xzb[(size_t)(mB + r2) * 1024 + n] = f2bf(acc[mi][ni][r2]);
      }
  }
  gbar(bar, 2);

  // ============ phase 2: conv+SiLU+gate+x_proj+dt_proj (2 iterations) ============
  {
    float (*xcs)[520] = (float(*)[520])smem;
    float (*dts)[16] = (float(*)[16])(smem + 4*520*4);
    for (int it = 0; it < 2; ++it) {
      __syncthreads();
      int r0 = (bid * 2 + it) * 4;
      int b = r0 >> 11;
      int l0 = r0 & (SEQ - 1);
      int rr = t >> 6;
      int dbase = (t & 63) * 8;
      int l = l0 + rr;
      size_t rowg = (size_t)b * SEQ + l;
      float acc[8];
      float4 cw[8];
#pragma unroll
      for (int dd = 0; dd < 8; ++dd) {
        cw[dd] = *reinterpret_cast<const float4*>(&conv_w[(dbase + dd) * 4]);
        acc[dd] = conv_b[dbase + dd];
      }
#pragma unroll
      for (int k = 0; k < 4; ++k) {
        int ls = l - 3 + k;
        if (ls >= 0) {
          ushort u[8];
          *reinterpret_cast<int4*>(u) =
            *reinterpret_cast<const int4*>(&xzb[((size_t)b * SEQ + ls) * 1024 + dbase]);
#pragma unroll
          for (int dd = 0; dd < 8; ++dd) {
            float wv = (k == 0) ? cw[dd].x : (k == 1) ? cw[dd].y : (k == 2) ? cw[dd].z : cw[dd].w;
            acc[dd] += bf2f(u[dd]) * wv;
          }
        }
      }
      {
        ushort uz[8], outx[8], outg[8];
        *reinterpret_cast<int4*>(uz) =
          *reinterpret_cast<const int4*>(&xzb[rowg * 1024 + 512 + dbase]);
#pragma unroll
        for (int dd = 0; dd < 8; ++dd) {
          float v = silu_f(acc[dd]);
          xcs[rr][dbase + dd] = v;
          outx[dd] = f2bf(v);
          outg[dd] = f2bf(silu_f(bf2f(uz[dd])));
        }
        *reinterpret_cast<int4*>(&xcb[rowg * 512 + dbase]) = *reinterpret_cast<int4*>(outx);
        *reinterpret_cast<int4*>(&gb [rowg * 512 + dbase]) = *reinterpret_cast<int4*>(outg);
      }
      __syncthreads();
      int lane = t & 15;
      int grp = t >> 4;
#pragma unroll
      for (int p = 0; p < 12; ++p) {
        int o = p * 16 + grp;
        int row = o / 48, e = o % 48;
        const float4* wv = reinterpret_cast<const float4*>(&xpw[e * 512]);
        const float4* av = reinterpret_cast<const float4*>(&xcs[row][0]);
        float s = 0.f;
#pragma unroll
        for (int k = 0; k < 8; ++k) {
          float4 a = av[lane + 16 * k];
          float4 w = wv[lane + 16 * k];
          s += a.x * w.x + a.y * w.y + a.z * w.z + a.w * w.w;
        }
        s += __shfl_xor(s, 1); s += __shfl_xor(s, 2); s += __shfl_xor(s, 4); s += __shfl_xor(s, 8);
        if (lane == 0) {
          if (e < 16) dts[row][e] = s;
          else BCbuf[(size_t)(r0 + row) * 32 + (e - 16)] = s;
        }
      }
      __syncthreads();
#pragma unroll
      for (int i = 0; i < 8; ++i) {
        int o = i * 256 + t;
        int row = o >> 9, d = o & 511;
        float s = dtb[d];
#pragma unroll
        for (int r = 0; r < 16; ++r) s += dts[row][r] * dtw[d * 16 + r];
        float sp = (s > 15.f) ? s : log1pf(__expf(s));
        delt[(size_t)(r0 + row) * 512 + d] = f2bf(sp);
      }
    }
  }
  gbar(bar, 3);

  // ============ phase 3: scan pass 1 -> P,S ============
  {
    float (*bcs)[32] = (float(*)[32])smem;
    int b = bid >> 8;
    int g = (bid >> 1) & 127;
    int dh = bid & 1;
    int d = dh * 256 + t;
    int base = b * SEQ + g * LCH;
    {
      float2 v = *reinterpret_cast<const float2*>(&BCbuf[(size_t)base * 32 + t * 2]);
      *reinterpret_cast<float2*>(&((float*)bcs)[t * 2]) = v;
    }
    __syncthreads();
    float an[16], h[16], P[16];
#pragma unroll
    for (int n = 0; n < 16; ++n) { an[n] = anv[n * 512 + d]; h[n] = 0.f; P[n] = 1.f; }
    for (int s = 0; s < LCH; ++s) {
      int row = base + s;
      float dl = bf2f(delt[(size_t)row * 512 + d]);
      float xv = bf2f(xcb[(size_t)row * 512 + d]);
      float dx = dl * xv;
#pragma unroll
      for (int n = 0; n < 16; ++n) {
        float dA = __expf(dl * an[n]);
        h[n] = dA * h[n] + dx * bcs[s][n];
        P[n] *= dA;
      }
    }
    size_t outb = ((size_t)(b * GCH + g) * 16) * 512 + d;
#pragma unroll
    for (int n = 0; n < 16; ++n) { Sbuf[outb + (size_t)n * 512] = h[n]; Pbuf[outb + (size_t)n * 512] = P[n]; }
  }
  gbar(bar, 4);

  // ============ phase 4: chunk combine -> Hinit ============
  {
    float* PL = (float*)smem;            // [8][32]
    float* SL = PL + 8 * 32;             // [8][32]
    int b = bid >> 8, n = (bid >> 4) & 15, d0 = (bid & 15) * 32;
    int j = t >> 5, dl = t & 31;
    int d = d0 + dl;
    const size_t gstr = (size_t)16 * 512;
    size_t base = ((size_t)(b * GCH) * 16 + n) * 512 + d;
    float P = 1.f, S = 0.f;
#pragma unroll
    for (int i = 0; i < 16; ++i) {
      size_t id = base + (size_t)(j * 16 + i) * gstr;
      float p = Pbuf[id], s = Sbuf[id];
      S = p * S + s; P *= p;
    }
    PL[j * 32 + dl] = P; SL[j * 32 + dl] = S;
    __syncthreads();
    if (t < 32) {
      float hp = 0.f;
      for (int jj = 0; jj < 8; ++jj) {
        float p = PL[jj * 32 + t], s = SL[jj * 32 + t];
        SL[jj * 32 + t] = hp;
        hp = p * hp + s;
      }
    }
    __syncthreads();
    float h = SL[j * 32 + dl];
#pragma unroll
    for (int i = 0; i < 16; ++i) {
      size_t id = base + (size_t)(j * 16 + i) * gstr;
      float p = Pbuf[id], s = Sbuf[id];
      Hinit[id] = h;
      h = p * h + s;
    }
  }
  gbar(bar, 5);

  // ============ phase 5: scan pass 2 + y + D-skip + gate -> ygb ============
  {
    float (*bcs)[32] = (float(*)[32])smem;
    int b = bid >> 8;
    int g = (bid >> 1) & 127;
    int dh = bid & 1;
    int d = dh * 256 + t;
    int base = b * SEQ + g * LCH;
    __syncthreads();
    {
      float2 v = *reinterpret_cast<const float2*>(&BCbuf[(size_t)base * 32 + t * 2]);
      *reinterpret_cast<float2*>(&((float*)bcs)[t * 2]) = v;
    }
    __syncthreads();
    float an[16], h[16];
    size_t hb0 = ((size_t)(b * GCH + g) * 16) * 512 + d;
#pragma unroll
    for (int n = 0; n < 16; ++n) { an[n] = anv[n * 512 + d]; h[n] = Hinit[hb0 + (size_t)n * 512]; }
    float Dd = Dw[d];
    for (int s = 0; s < LCH; ++s) {
      int row = base + s;
      float dl = bf2f(delt[(size_t)row * 512 + d]);
      float xv = bf2f(xcb[(size_t)row * 512 + d]);
      float dx = dl * xv;
      float y = 0.f;
#pragma unroll
      for (int n = 0; n < 16; ++n) {
        float dA = __expf(dl * an[n]);
        h[n] = dA * h[n] + dx * bcs[s][n];
        y += h[n] * bcs[s][16 + n];
      }
      float zg = bf2f(gb[(size_t)row * 512 + d]);
      ygb[(size_t)row * 512 + d] = f2bf((y + xv * Dd) * zg);
    }
  }
  gbar(bar, 6);

  // ============ phase 6: GEMM3 (bf16 MFMA) 64x64 tiles + residual -> out ============
  if (bid < 256) {
    ushort (*Als)[72] = (ushort(*)[72])smem;
    ushort (*Bls)[72] = (ushort(*)[72])(smem + 64*72*2);
    int m0 = (bid >> 2) * 64, n0 = (bid & 3) * 64;
    int w = t >> 6, l = t & 63;
    int wr = w >> 1, wc = w & 1;
    f32x4 acc[2][2] = {};
    int sr = t >> 3, sc = t & 7;
    for (int k0 = 0; k0 < DINNER; k0 += 64) {
#pragma unroll
      for (int p = 0; p < 2; ++p) {
        int r = sr + p * 32;
        *reinterpret_cast<int4*>(&Als[r][sc * 8]) =
          *reinterpret_cast<const int4*>(&ygb[((size_t)(m0 + r)) * DINNER + k0 + sc * 8]);
        *reinterpret_cast<int4*>(&Bls[r][sc * 8]) =
          *reinterpret_cast<const int4*>(&wob[((size_t)(n0 + r)) * DINNER + k0 + sc * 8]);
      }
      __syncthreads();
#pragma unroll
      for (int ks = 0; ks < 2; ++ks) {
        s16x8 af[2], bf[2];
        int kk = ks * 32 + 8 * (l >> 4);
#pragma unroll
        for (int i = 0; i < 2; ++i) {
          af[i] = *reinterpret_cast<const s16x8*>(&Als[wr * 32 + i * 16 + (l & 15)][kk]);
          bf[i] = *reinterpret_cast<const s16x8*>(&Bls[wc * 32 + i * 16 + (l & 15)][kk]);
        }
#pragma unroll
        for (int mi = 0; mi < 2; ++mi)
#pragma unroll
          for (int ni = 0; ni < 2; ++ni)
            acc[mi][ni] = __builtin_amdgcn_mfma_f32_16x16x32_bf16(af[mi], bf[ni], acc[mi][ni], 0, 0, 0);
      }
      __syncthreads();
    }
    int rq = l >> 4, cc = l & 15;
#pragma unroll
    for (int mi = 0; mi < 2; ++mi)
#pragma unroll
      for (int ni = 0; ni < 2; ++ni) {
        int n = n0 + wc * 32 + ni * 16 + cc;
        int mB = m0 + wr * 32 + mi * 16 + rq * 4;
#pragma unroll
        for (int r2 = 0; r2 < 4; ++r2) {
          int m = mB + r2;
          int b = m >> 11;
          int lb = m & (SEQ - 1);
          size_t addr = ((size_t)(b * DMODEL + n)) * SEQ + lb;
          out[addr] = acc[mi][ni][r2] + x[addr];
        }
      }
  }
}

extern "C" void kernel_launch(void* const* d_in, const int* in_sizes, int n_in,
                              void* d_out, int out_size, void* d_ws, size_t ws_size,
                              hipStream_t stream) {
  const float* x          = (const float*)d_in[0];
  const float* norm_w     = (const float*)d_in[1];
  const float* in_proj_w  = (const float*)d_in[2];
  const float* conv_w     = (const float*)d_in[3];
  const float* conv_b     = (const float*)d_in[4];
  const float* x_proj_w   = (const float*)d_in[5];
  const float* dt_proj_w  = (const float*)d_in[6];
  const float* dt_proj_b  = (const float*)d_in[7];
  const float* A_log      = (const float*)d_in[8];
  const float* Dw         = (const float*)d_in[9];
  const float* out_proj_w = (const float*)d_in[10];
  float* out = (float*)d_out;
  float* ws  = (float*)d_ws;

  hipMemsetAsync(d_ws, 0, 64, stream);   // zero barrier state (count + epoch)
  k_mega<<<512, 256, 0, stream>>>(x, norm_w, in_proj_w, conv_w, conv_b,
                                  x_proj_w, dt_proj_w, dt_proj_b, A_log, Dw,
                                  out_proj_w, out, ws);
}

// Round 7
// 486.366 us; speedup vs baseline: 1.5868x; 1.5868x over previous
//
#include <hip/hip_runtime.h>
#include <hip/hip_bf16.h>
#include <math.h>

#define BATCH  2
#define SEQ    2048
#define DMODEL 256
#define DSTATE 16
#define DINNER 512
#define RTOT   4096
#define GCH    128
#define LCH    16
#define NW1    (2*DINNER*DMODEL)   // 262144
#define NW2    (DMODEL*DINNER)     // 131072

typedef float f32x4 __attribute__((ext_vector_type(4)));
typedef short s16x8 __attribute__((ext_vector_type(8)));

__device__ __forceinline__ float silu_f(float v){ return v / (1.f + __expf(-v)); }
__device__ __forceinline__ ushort f2bf(float f){
  __hip_bfloat16 h = __float2bfloat16(f);
  return *reinterpret_cast<ushort*>(&h);
}
__device__ __forceinline__ float bf2f(ushort u){
  union { unsigned int i; float f; } c; c.i = ((unsigned int)u) << 16; return c.f;
}

// ---- workspace layout (float offsets from ws base) ----
#define OFF_BC    16
#define OFF_P     (OFF_BC + RTOT*32)
#define OFF_S     (OFF_P + 2*GCH*16*512)
#define OFF_H     (OFF_S + 2*GCH*16*512)
#define OFF_ANV   (OFF_H + 2*GCH*16*512)
#define OFF_US    (OFF_ANV + 16*512)
// ushort offsets relative to ushort region
#define UOFF_HB   ((size_t)0)
#define UOFF_WIB  (UOFF_HB + (size_t)RTOT*DMODEL)
#define UOFF_WOB  (UOFF_WIB + (size_t)NW1)
#define UOFF_XZ   (UOFF_WOB + (size_t)NW2)
#define UOFF_XC   (UOFF_XZ + (size_t)RTOT*1024)
#define UOFF_G    (UOFF_XC + (size_t)RTOT*512)
#define UOFF_DL   (UOFF_G  + (size_t)RTOT*512)
#define UOFF_YG   (UOFF_DL + (size_t)RTOT*512)

// grid-wide epoch barrier. Poll RELAXED (no cache invalidation per poll —
// agent-scope atomics bypass the non-coherent XCD L2), fence once on exit.
// Round-5 lesson: ACQUIRE inside the spin loop = L2 invalidate per poll = 5x regression.
__device__ __forceinline__ void gbar(int* bar, int id){
  __syncthreads();
  if (threadIdx.x == 0) {
    __builtin_amdgcn_fence(__ATOMIC_RELEASE, "agent");
    int old = __hip_atomic_fetch_add(&bar[0], 1, __ATOMIC_RELAXED, __HIP_MEMORY_SCOPE_AGENT);
    if (old == (int)gridDim.x - 1) {
      __hip_atomic_store(&bar[0], 0, __ATOMIC_RELAXED, __HIP_MEMORY_SCOPE_AGENT);
      __hip_atomic_store(&bar[1], id, __ATOMIC_RELAXED, __HIP_MEMORY_SCOPE_AGENT);
    } else {
      for (int k = 0; k < (1 << 22); ++k) {
        if (__hip_atomic_load(&bar[1], __ATOMIC_RELAXED, __HIP_MEMORY_SCOPE_AGENT) >= id) break;
        __builtin_amdgcn_s_sleep(8);
      }
    }
    __builtin_amdgcn_fence(__ATOMIC_ACQUIRE, "agent");
  }
  __syncthreads();
}

__global__ __launch_bounds__(256, 2) void k_mega(
    const float* __restrict__ x,
    const float* __restrict__ norm_w,
    const float* __restrict__ w_in,
    const float* __restrict__ conv_w,
    const float* __restrict__ conv_b,
    const float* __restrict__ xpw,
    const float* __restrict__ dtw,
    const float* __restrict__ dtb,
    const float* __restrict__ A_log,
    const float* __restrict__ Dw,
    const float* __restrict__ w_out,
    float* __restrict__ out,
    float* __restrict__ ws){
  __shared__ __align__(16) char smem[36864];
  int* bar = (int*)ws;
  float* BCbuf = ws + OFF_BC;
  float* Pbuf  = ws + OFF_P;
  float* Sbuf  = ws + OFF_S;
  float* Hinit = ws + OFF_H;
  float* anv   = ws + OFF_ANV;
  ushort* ub   = (ushort*)(ws + OFF_US);
  ushort* hb   = ub + UOFF_HB;
  ushort* wib  = ub + UOFF_WIB;
  ushort* wob  = ub + UOFF_WOB;
  ushort* xzb  = ub + UOFF_XZ;
  ushort* xcb  = ub + UOFF_XC;
  ushort* gb   = ub + UOFF_G;
  ushort* delt = ub + UOFF_DL;
  ushort* ygb  = ub + UOFF_YG;

  int bid = blockIdx.x;
  int t = threadIdx.x;

  // ============ phase 0: RMSNorm+transpose | weight cvt | A-table ============
  if (bid < 64) {
    ushort (*Ls)[272] = (ushort(*)[272])smem;
    float (*red)[64] = (float(*)[64])(smem + 64*272*2);
    int b = bid >> 5, l0 = (bid & 31) << 6;
    int ll = t & 63, cq = t >> 6;
    const float* xb = x + (size_t)b * DMODEL * SEQ;
    float ss = 0.f;
    for (int it = 0; it < 64; ++it) {
      int c = cq * 64 + it;
      float v = xb[(size_t)c * SEQ + l0 + ll];
      ss += v * v;
    }
    red[cq][ll] = ss;
    __syncthreads();
    float s = red[0][ll] + red[1][ll] + red[2][ll] + red[3][ll];
    float r = rsqrtf(s * (1.f / DMODEL) + 1e-5f);
    for (int it = 0; it < 64; ++it) {
      int c = cq * 64 + it;
      float v = xb[(size_t)c * SEQ + l0 + ll];
      Ls[ll][c] = f2bf(v * r * norm_w[c]);
    }
    __syncthreads();
    int row = t >> 2;
#pragma unroll
    for (int i = 0; i < 8; ++i) {
      int ch = (t & 3) + i * 4;
      int4 v = *reinterpret_cast<const int4*>(&Ls[row][ch * 8]);
      *reinterpret_cast<int4*>(&hb[((size_t)(b * SEQ + l0 + row)) * DMODEL + ch * 8]) = v;
    }
  } else if (bid < 448) {
    int base = (bid - 64) * 1024 + t * 4;
    if (base < NW1) {
      float4 v = *reinterpret_cast<const float4*>(&w_in[base]);
      ushort4 o; o.x = f2bf(v.x); o.y = f2bf(v.y); o.z = f2bf(v.z); o.w = f2bf(v.w);
      *reinterpret_cast<ushort4*>(&wib[base]) = o;
    } else {
      int j = base - NW1;
      float4 v = *reinterpret_cast<const float4*>(&w_out[j]);
      ushort4 o; o.x = f2bf(v.x); o.y = f2bf(v.y); o.z = f2bf(v.z); o.w = f2bf(v.w);
      *reinterpret_cast<ushort4*>(&wob[j]) = o;
    }
  } else if (bid < 450) {
    int d = (bid - 448) * 256 + t;
#pragma unroll
    for (int n = 0; n < 16; ++n)
      anv[n * 512 + d] = -__expf(A_log[d * 16 + n]);
  }
  gbar(bar, 1);

  // ============ phase 1: GEMM1 (bf16 MFMA) 128x64 tiles -> xzb ============
  {
    ushort (*Als)[72] = (ushort(*)[72])smem;
    ushort (*Bls)[72] = (ushort(*)[72])(smem + 128*72*2);
    int m0 = (bid >> 4) * 128, n0 = (bid & 15) * 64;
    int w = t >> 6, l = t & 63;
    int wr = w >> 1, wc = w & 1;
    f32x4 acc[4][2] = {};
    int sr = t >> 3, sc = t & 7;
    for (int k0 = 0; k0 < DMODEL; k0 += 64) {
#pragma unroll
      for (int p = 0; p < 4; ++p) {
        int r = sr + p * 32;
        *reinterpret_cast<int4*>(&Als[r][sc * 8]) =
          *reinterpret_cast<const int4*>(&hb[((size_t)(m0 + r)) * DMODEL + k0 + sc * 8]);
      }
#pragma unroll
      for (int p = 0; p < 2; ++p) {
        int r = sr + p * 32;
        *reinterpret_cast<int4*>(&Bls[r][sc * 8]) =
          *reinterpret_cast<const int4*>(&wib[((size_t)(n0 + r)) * DMODEL + k0 + sc * 8]);
      }
      __syncthreads();
#pragma unroll
      for (int ks = 0; ks < 2; ++ks) {
        s16x8 af[4], bf[2];
        int kk = ks * 32 + 8 * (l >> 4);
#pragma unroll
        for (int i = 0; i < 4; ++i)
          af[i] = *reinterpret_cast<const s16x8*>(&Als[wr * 64 + i * 16 + (l & 15)][kk]);
#pragma unroll
        for (int i = 0; i < 2; ++i)
          bf[i] = *reinterpret_cast<const s16x8*>(&Bls[wc * 32 + i * 16 + (l & 15)][kk]);
#pragma unroll
        for (int mi = 0; mi < 4; ++mi)
#pragma unroll
          for (int ni = 0; ni < 2; ++ni)
            acc[mi][ni] = __builtin_amdgcn_mfma_f32_16x16x32_bf16(af[mi], bf[ni], acc[mi][ni], 0, 0, 0);
      }
      __syncthreads();
    }
    int rq = l >> 4, cc = l & 15;
#pragma unroll
    for (int mi = 0; mi < 4; ++mi)
#pragma unroll
      for (int ni = 0; ni < 2; ++ni) {
        int n = n0 + wc * 32 + ni * 16 + cc;
        int mB = m0 + wr * 64 + mi * 16 + rq * 4;
#pragma unroll
        for (int r2 = 0; r2 < 4; ++r2)
          xzb[(size_t)(mB + r2) * 1024 + n] = f2bf(acc[mi][ni][r2]);
      }
  }
  gbar(bar, 2);

  // ============ phase 2: conv+SiLU+gate+x_proj+dt_proj (2 iterations) ============
  {
    float (*xcs)[520] = (float(*)[520])smem;
    float (*dts)[16] = (float(*)[16])(smem + 4*520*4);
    for (int it = 0; it < 2; ++it) {
      __syncthreads();
      int r0 = (bid * 2 + it) * 4;
      int b = r0 >> 11;
      int l0 = r0 & (SEQ - 1);
      int rr = t >> 6;
      int dbase = (t & 63) * 8;
      int l = l0 + rr;
      size_t rowg = (size_t)b * SEQ + l;
      float acc[8];
      float4 cw[8];
#pragma unroll
      for (int dd = 0; dd < 8; ++dd) {
        cw[dd] = *reinterpret_cast<const float4*>(&conv_w[(dbase + dd) * 4]);
        acc[dd] = conv_b[dbase + dd];
      }
#pragma unroll
      for (int k = 0; k < 4; ++k) {
        int ls = l - 3 + k;
        if (ls >= 0) {
          ushort u[8];
          *reinterpret_cast<int4*>(u) =
            *reinterpret_cast<const int4*>(&xzb[((size_t)b * SEQ + ls) * 1024 + dbase]);
#pragma unroll
          for (int dd = 0; dd < 8; ++dd) {
            float wv = (k == 0) ? cw[dd].x : (k == 1) ? cw[dd].y : (k == 2) ? cw[dd].z : cw[dd].w;
            acc[dd] += bf2f(u[dd]) * wv;
          }
        }
      }
      {
        ushort uz[8], outx[8], outg[8];
        *reinterpret_cast<int4*>(uz) =
          *reinterpret_cast<const int4*>(&xzb[rowg * 1024 + 512 + dbase]);
#pragma unroll
        for (int dd = 0; dd < 8; ++dd) {
          float v = silu_f(acc[dd]);
          xcs[rr][dbase + dd] = v;
          outx[dd] = f2bf(v);
          outg[dd] = f2bf(silu_f(bf2f(uz[dd])));
        }
        *reinterpret_cast<int4*>(&xcb[rowg * 512 + dbase]) = *reinterpret_cast<int4*>(outx);
        *reinterpret_cast<int4*>(&gb [rowg * 512 + dbase]) = *reinterpret_cast<int4*>(outg);
      }
      __syncthreads();
      int lane = t & 15;
      int grp = t >> 4;
#pragma unroll
      for (int p = 0; p < 12; ++p) {
        int o = p * 16 + grp;
        int row = o / 48, e = o % 48;
        const float4* wv = reinterpret_cast<const float4*>(&xpw[e * 512]);
        const float4* av = reinterpret_cast<const float4*>(&xcs[row][0]);
        float s = 0.f;
#pragma unroll
        for (int k = 0; k < 8; ++k) {
          float4 a = av[lane + 16 * k];
          float4 w = wv[lane + 16 * k];
          s += a.x * w.x + a.y * w.y + a.z * w.z + a.w * w.w;
        }
        s += __shfl_xor(s, 1); s += __shfl_xor(s, 2); s += __shfl_xor(s, 4); s += __shfl_xor(s, 8);
        if (lane == 0) {
          if (e < 16) dts[row][e] = s;
          else BCbuf[(size_t)(r0 + row) * 32 + (e - 16)] = s;
        }
      }
      __syncthreads();
#pragma unroll
      for (int i = 0; i < 8; ++i) {
        int o = i * 256 + t;
        int row = o >> 9, d = o & 511;
        float s = dtb[d];
#pragma unroll
        for (int r = 0; r < 16; ++r) s += dts[row][r] * dtw[d * 16 + r];
        float sp = (s > 15.f) ? s : log1pf(__expf(s));
        delt[(size_t)(r0 + row) * 512 + d] = f2bf(sp);
      }
    }
  }
  gbar(bar, 3);

  // ============ phase 3: scan pass 1 -> P,S ============
  {
    float (*bcs)[32] = (float(*)[32])smem;
    int b = bid >> 8;
    int g = (bid >> 1) & 127;
    int dh = bid & 1;
    int d = dh * 256 + t;
    int base = b * SEQ + g * LCH;
    {
      float2 v = *reinterpret_cast<const float2*>(&BCbuf[(size_t)base * 32 + t * 2]);
      *reinterpret_cast<float2*>(&((float*)bcs)[t * 2]) = v;
    }
    __syncthreads();
    float an[16], h[16], P[16];
#pragma unroll
    for (int n = 0; n < 16; ++n) { an[n] = anv[n * 512 + d]; h[n] = 0.f; P[n] = 1.f; }
    for (int s = 0; s < LCH; ++s) {
      int row = base + s;
      float dl = bf2f(delt[(size_t)row * 512 + d]);
      float xv = bf2f(xcb[(size_t)row * 512 + d]);
      float dx = dl * xv;
#pragma unroll
      for (int n = 0; n < 16; ++n) {
        float dA = __expf(dl * an[n]);
        h[n] = dA * h[n] + dx * bcs[s][n];
        P[n] *= dA;
      }
    }
    size_t outb = ((size_t)(b * GCH + g) * 16) * 512 + d;
#pragma unroll
    for (int n = 0; n < 16; ++n) { Sbuf[outb + (size_t)n * 512] = h[n]; Pbuf[outb + (size_t)n * 512] = P[n]; }
  }
  gbar(bar, 4);

  // ============ phase 4: chunk combine -> Hinit ============
  {
    float* PL = (float*)smem;            // [8][32]
    float* SL = PL + 8 * 32;             // [8][32]
    int b = bid >> 8, n = (bid >> 4) & 15, d0 = (bid & 15) * 32;
    int j = t >> 5, dl = t & 31;
    int d = d0 + dl;
    const size_t gstr = (size_t)16 * 512;
    size_t base = ((size_t)(b * GCH) * 16 + n) * 512 + d;
    float P = 1.f, S = 0.f;
#pragma unroll
    for (int i = 0; i < 16; ++i) {
      size_t id = base + (size_t)(j * 16 + i) * gstr;
      float p = Pbuf[id], s = Sbuf[id];
      S = p * S + s; P *= p;
    }
    PL[j * 32 + dl] = P; SL[j * 32 + dl] = S;
    __syncthreads();
    if (t < 32) {
      float hp = 0.f;
      for (int jj = 0; jj < 8; ++jj) {
        float p = PL[jj * 32 + t], s = SL[jj * 32 + t];
        SL[jj * 32 + t] = hp;
        hp = p * hp + s;
      }
    }
    __syncthreads();
    float h = SL[j * 32 + dl];
#pragma unroll
    for (int i = 0; i < 16; ++i) {
      size_t id = base + (size_t)(j * 16 + i) * gstr;
      float p = Pbuf[id], s = Sbuf[id];
      Hinit[id] = h;
      h = p * h + s;
    }
  }
  gbar(bar, 5);

  // ============ phase 5: scan pass 2 + y + D-skip + gate -> ygb ============
  {
    float (*bcs)[32] = (float(*)[32])smem;
    int b = bid >> 8;
    int g = (bid >> 1) & 127;
    int dh = bid & 1;
    int d = dh * 256 + t;
    int base = b * SEQ + g * LCH;
    __syncthreads();
    {
      float2 v = *reinterpret_cast<const float2*>(&BCbuf[(size_t)base * 32 + t * 2]);
      *reinterpret_cast<float2*>(&((float*)bcs)[t * 2]) = v;
    }
    __syncthreads();
    float an[16], h[16];
    size_t hb0 = ((size_t)(b * GCH + g) * 16) * 512 + d;
#pragma unroll
    for (int n = 0; n < 16; ++n) { an[n] = anv[n * 512 + d]; h[n] = Hinit[hb0 + (size_t)n * 512]; }
    float Dd = Dw[d];
    for (int s = 0; s < LCH; ++s) {
      int row = base + s;
      float dl = bf2f(delt[(size_t)row * 512 + d]);
      float xv = bf2f(xcb[(size_t)row * 512 + d]);
      float dx = dl * xv;
      float y = 0.f;
#pragma unroll
      for (int n = 0; n < 16; ++n) {
        float dA = __expf(dl * an[n]);
        h[n] = dA * h[n] + dx * bcs[s][n];
        y += h[n] * bcs[s][16 + n];
      }
      float zg = bf2f(gb[(size_t)row * 512 + d]);
      ygb[(size_t)row * 512 + d] = f2bf((y + xv * Dd) * zg);
    }
  }
  gbar(bar, 6);

  // ============ phase 6: GEMM3 (bf16 MFMA) 64x64 tiles + residual -> out ============
  if (bid < 256) {
    ushort (*Als)[72] = (ushort(*)[72])smem;
    ushort (*Bls)[72] = (ushort(*)[72])(smem + 64*72*2);
    int m0 = (bid >> 2) * 64, n0 = (bid & 3) * 64;
    int w = t >> 6, l = t & 63;
    int wr = w >> 1, wc = w & 1;
    f32x4 acc[2][2] = {};
    int sr = t >> 3, sc = t & 7;
    for (int k0 = 0; k0 < DINNER; k0 += 64) {
#pragma unroll
      for (int p = 0; p < 2; ++p) {
        int r = sr + p * 32;
        *reinterpret_cast<int4*>(&Als[r][sc * 8]) =
          *reinterpret_cast<const int4*>(&ygb[((size_t)(m0 + r)) * DINNER + k0 + sc * 8]);
        *reinterpret_cast<int4*>(&Bls[r][sc * 8]) =
          *reinterpret_cast<const int4*>(&wob[((size_t)(n0 + r)) * DINNER + k0 + sc * 8]);
      }
      __syncthreads();
#pragma unroll
      for (int ks = 0; ks < 2; ++ks) {
        s16x8 af[2], bf[2];
        int kk = ks * 32 + 8 * (l >> 4);
#pragma unroll
        for (int i = 0; i < 2; ++i) {
          af[i] = *reinterpret_cast<const s16x8*>(&Als[wr * 32 + i * 16 + (l & 15)][kk]);
          bf[i] = *reinterpret_cast<const s16x8*>(&Bls[wc * 32 + i * 16 + (l & 15)][kk]);
        }
#pragma unroll
        for (int mi = 0; mi < 2; ++mi)
#pragma unroll
          for (int ni = 0; ni < 2; ++ni)
            acc[mi][ni] = __builtin_amdgcn_mfma_f32_16x16x32_bf16(af[mi], bf[ni], acc[mi][ni], 0, 0, 0);
      }
      __syncthreads();
    }
    int rq = l >> 4, cc = l & 15;
#pragma unroll
    for (int mi = 0; mi < 2; ++mi)
#pragma unroll
      for (int ni = 0; ni < 2; ++ni) {
        int n = n0 + wc * 32 + ni * 16 + cc;
        int mB = m0 + wr * 32 + mi * 16 + rq * 4;
#pragma unroll
        for (int r2 = 0; r2 < 4; ++r2) {
          int m = mB + r2;
          int b = m >> 11;
          int lb = m & (SEQ - 1);
          size_t addr = ((size_t)(b * DMODEL + n)) * SEQ + lb;
          out[addr] = acc[mi][ni][r2] + x[addr];
        }
      }
  }
}

extern "C" void kernel_launch(void* const* d_in, const int* in_sizes, int n_in,
                              void* d_out, int out_size, void* d_ws, size_t ws_size,
                              hipStream_t stream) {
  const float* x          = (const float*)d_in[0];
  const float* norm_w     = (const float*)d_in[1];
  const float* in_proj_w  = (const float*)d_in[2];
  const float* conv_w     = (const float*)d_in[3];
  const float* conv_b     = (const float*)d_in[4];
  const float* x_proj_w   = (const float*)d_in[5];
  const float* dt_proj_w  = (const float*)d_in[6];
  const float* dt_proj_b  = (const float*)d_in[7];
  const float* A_log      = (const float*)d_in[8];
  const float* Dw         = (const float*)d_in[9];
  const float* out_proj_w = (const float*)d_in[10];
  float* out = (float*)d_out;
  float* ws  = (float*)d_ws;

  (void)hipMemsetAsync(d_ws, 0, 64, stream);   // zero barrier state (count + epoch)
  k_mega<<<512, 256, 0, stream>>>(x, norm_w, in_proj_w, conv_w, conv_b,
                                  x_proj_w, dt_proj_w, dt_proj_b, A_log, Dw,
                                  out_proj_w, out, ws);
}

// Round 8
// 100.973 us; speedup vs baseline: 7.6431x; 4.8168x over previous
//
#include <hip/hip_runtime.h>
#include <hip/hip_bf16.h>
#include <math.h>

#define BATCH  2
#define SEQ    2048
#define DMODEL 256
#define DSTATE 16
#define DINNER 512
#define RTOT   4096
#define GCH    128
#define LCH    16
#define NW2    (DMODEL*DINNER)     // 131072

typedef float f32x4 __attribute__((ext_vector_type(4)));
typedef short s16x8 __attribute__((ext_vector_type(8)));

__device__ __forceinline__ float silu_f(float v){ return v / (1.f + __expf(-v)); }
__device__ __forceinline__ ushort f2bf(float f){
  __hip_bfloat16 h = __float2bfloat16(f);
  return *reinterpret_cast<ushort*>(&h);
}
__device__ __forceinline__ float bf2f(ushort u){
  union { unsigned int i; float f; } c; c.i = ((unsigned int)u) << 16; return c.f;
}

// ---- workspace layout (float offsets) ----
#define OFF_BC   0
#define OFF_S    (OFF_BC + RTOT*32)          // S: 2*128*16*512
#define OFF_H    (OFF_S + 2*GCH*16*512)      // Hinit
#define OFF_ANV  (OFF_H + 2*GCH*16*512)      // 16*512
#define OFF_SD   (OFF_ANV + 16*512)          // sumd: 2*128*512
#define OFF_US   (OFF_SD + 2*GCH*512)
#define UOFF_WOB ((size_t)0)
#define UOFF_XZ  (UOFF_WOB + (size_t)NW2)
#define UOFF_XC  (UOFF_XZ + (size_t)RTOT*1024)
#define UOFF_G   (UOFF_XC + (size_t)RTOT*512)
#define UOFF_DL  (UOFF_G  + (size_t)RTOT*512)
#define UOFF_YG  (UOFF_DL + (size_t)RTOT*512)

// ======== kernel 1: RMSNorm-into-LDS + B-panel cvt + GEMM1 (128x128) + wob/anv tails ========
__global__ __launch_bounds__(256) void k_g1(const float* __restrict__ x,
                                            const float* __restrict__ norm_w,
                                            const float* __restrict__ w_in,
                                            const float* __restrict__ w_out,
                                            const float* __restrict__ A_log,
                                            ushort* __restrict__ wob,
                                            float* __restrict__ anv,
                                            ushort* __restrict__ xzb){
  __shared__ ushort As[128][264];
  __shared__ ushort Bls[128][264];
  __shared__ float red[4][64];
  int bid = blockIdx.x;
  int t = threadIdx.x;
  // tails: out_proj cvt (512 elems/block) + A-table (blocks 0..31)
  {
    int base = bid * 512 + (t & 127) * 4;
    if (t < 128) {
      float4 v = *reinterpret_cast<const float4*>(&w_out[base]);
      ushort4 o; o.x = f2bf(v.x); o.y = f2bf(v.y); o.z = f2bf(v.z); o.w = f2bf(v.w);
      *reinterpret_cast<ushort4*>(&wob[base]) = o;
    }
    if (bid < 32) {
      int e = bid * 256 + t;           // e = n*512 + d
      int n = e >> 9, d = e & 511;
      anv[e] = -__expf(A_log[d * 16 + n]);
    }
  }
  int mB = bid >> 3, nB = bid & 7;
  int m0 = mB * 128, n0 = nB * 128;
  int b = mB >> 4;
  int l0 = (mB & 15) << 7;
  const float* xb = x + (size_t)b * DMODEL * SEQ;
  int ll = t & 63, cq = t >> 6;
  // ---- RMSNorm into As (two 64-row halves) ----
  for (int half = 0; half < 2; ++half) {
    int l = l0 + half * 64 + ll;
    float ss = 0.f;
    for (int it = 0; it < 64; ++it) {
      int c = cq * 64 + it;
      float v = xb[(size_t)c * SEQ + l];
      ss += v * v;
    }
    red[cq][ll] = ss;
    __syncthreads();
    float s = red[0][ll] + red[1][ll] + red[2][ll] + red[3][ll];
    float r = rsqrtf(s * (1.f / DMODEL) + 1e-5f);
    for (int it = 0; it < 64; ++it) {
      int c = cq * 64 + it;
      float v = xb[(size_t)c * SEQ + l];
      As[half * 64 + ll][c] = f2bf(v * r * norm_w[c]);
    }
    __syncthreads();
  }
  // ---- B-panel cvt into Bls ----
  {
    int r = t >> 1, ch = t & 1;
    const float* wr_ = &w_in[(size_t)(n0 + r) * DMODEL + ch * 128];
#pragma unroll
    for (int j = 0; j < 32; ++j) {
      float4 v = *reinterpret_cast<const float4*>(&wr_[j * 4]);
      ushort4 o; o.x = f2bf(v.x); o.y = f2bf(v.y); o.z = f2bf(v.z); o.w = f2bf(v.w);
      *reinterpret_cast<ushort4*>(&Bls[r][ch * 128 + j * 4]) = o;
    }
  }
  __syncthreads();
  // ---- GEMM from LDS (K=256, no restaging) ----
  int w = t >> 6, l = t & 63;
  int wr = w >> 1, wc = w & 1;
  f32x4 acc[4][4] = {};
#pragma unroll
  for (int ks = 0; ks < 8; ++ks) {
    int kk = ks * 32 + 8 * (l >> 4);
    s16x8 af[4], bf[4];
#pragma unroll
    for (int i = 0; i < 4; ++i) {
      af[i] = *reinterpret_cast<const s16x8*>(&As[wr * 64 + i * 16 + (l & 15)][kk]);
      bf[i] = *reinterpret_cast<const s16x8*>(&Bls[wc * 64 + i * 16 + (l & 15)][kk]);
    }
#pragma unroll
    for (int mi = 0; mi < 4; ++mi)
#pragma unroll
      for (int ni = 0; ni < 4; ++ni)
        acc[mi][ni] = __builtin_amdgcn_mfma_f32_16x16x32_bf16(af[mi], bf[ni], acc[mi][ni], 0, 0, 0);
  }
  int rq = l >> 4, cc = l & 15;
#pragma unroll
  for (int mi = 0; mi < 4; ++mi)
#pragma unroll
    for (int ni = 0; ni < 4; ++ni) {
      int n = n0 + wc * 64 + ni * 16 + cc;
      int mB2 = m0 + wr * 64 + mi * 16 + rq * 4;
#pragma unroll
      for (int r2 = 0; r2 < 4; ++r2)
        xzb[(size_t)(mB2 + r2) * 1024 + n] = f2bf(acc[mi][ni][r2]);
    }
}

// ======== kernel 2: conv+SiLU+gate+x_proj+dt_proj+scan1 fused; block = (b, 16-row chunk) ========
__global__ __launch_bounds__(256) void k_cs1(const ushort* __restrict__ xzb,
                                             const float* __restrict__ conv_w,
                                             const float* __restrict__ conv_b,
                                             const float* __restrict__ xpw,
                                             const float* __restrict__ dtw,
                                             const float* __restrict__ dtb,
                                             const float* __restrict__ anv,
                                             ushort* __restrict__ xcb,
                                             ushort* __restrict__ gb,
                                             float* __restrict__ BCbuf,
                                             ushort* __restrict__ delt,
                                             float* __restrict__ Sbuf,
                                             float* __restrict__ sumd){
  __shared__ ushort xin_s[19][520];
  __shared__ float xcs[16][520];
  __shared__ ushort dlt_s[16][520];
  __shared__ float bcs[16][32];
  __shared__ float dts[16][16];
  int bid = blockIdx.x;            // 256 = b(1) g(7)
  int b = bid >> 7;
  int g = bid & 127;
  int t = threadIdx.x;
  int base = b * SEQ + g * LCH;
  // stage xin rows [g*16-3, g*16+16) and produce gate
#pragma unroll
  for (int i = 0; i < 5; ++i) {
    int slot = i * 256 + t;
    if (slot < 1216) {
      int rr = slot >> 6, c16 = slot & 63;
      int lloc = g * LCH - 3 + rr;
      int4 v = make_int4(0, 0, 0, 0);
      if (lloc >= 0)
        v = *reinterpret_cast<const int4*>(&xzb[((size_t)(b * SEQ + lloc)) * 1024 + c16 * 8]);
      *reinterpret_cast<int4*>(&xin_s[rr][c16 * 8]) = v;
    }
  }
#pragma unroll
  for (int i = 0; i < 4; ++i) {
    int slot = i * 256 + t;
    int rr = slot >> 6, c16 = slot & 63;
    ushort u[8], o[8];
    *reinterpret_cast<int4*>(u) =
      *reinterpret_cast<const int4*>(&xzb[((size_t)(base + rr)) * 1024 + 512 + c16 * 8]);
#pragma unroll
    for (int k = 0; k < 8; ++k) o[k] = f2bf(silu_f(bf2f(u[k])));
    *reinterpret_cast<int4*>(&gb[((size_t)(base + rr)) * 512 + c16 * 8]) = *reinterpret_cast<int4*>(o);
  }
  __syncthreads();
  // conv + SiLU: thread t owns d = 2t, 2t+1
  {
    int d0 = t * 2;
    float4 cw0 = *reinterpret_cast<const float4*>(&conv_w[d0 * 4]);
    float4 cw1 = *reinterpret_cast<const float4*>(&conv_w[d0 * 4 + 4]);
    float b0 = conv_b[d0], b1 = conv_b[d0 + 1];
#pragma unroll
    for (int r = 0; r < 16; ++r) {
      float a0 = b0, a1 = b1;
#pragma unroll
      for (int k = 0; k < 4; ++k) {
        float x0 = bf2f(xin_s[r + k][d0]);
        float x1 = bf2f(xin_s[r + k][d0 + 1]);
        float w0 = (k == 0) ? cw0.x : (k == 1) ? cw0.y : (k == 2) ? cw0.z : cw0.w;
        float w1 = (k == 0) ? cw1.x : (k == 1) ? cw1.y : (k == 2) ? cw1.z : cw1.w;
        a0 += x0 * w0; a1 += x1 * w1;
      }
      float v0 = silu_f(a0), v1 = silu_f(a1);
      xcs[r][d0] = v0; xcs[r][d0 + 1] = v1;
      ushort2 o; o.x = f2bf(v0); o.y = f2bf(v1);
      *reinterpret_cast<ushort2*>(&xcb[((size_t)(base + r)) * 512 + d0]) = o;
    }
  }
  __syncthreads();
  // x_proj: 768 outs = 16 rows x 48; 16-lane K-split + shfl reduce
  {
    int lane = t & 15;
    int grp = t >> 4;
#pragma unroll
    for (int p = 0; p < 48; ++p) {
      int o = p * 16 + grp;
      int row = o / 48, e = o % 48;
      const float4* wv = reinterpret_cast<const float4*>(&xpw[e * 512]);
      const float4* av = reinterpret_cast<const float4*>(&xcs[row][0]);
      float s = 0.f;
#pragma unroll
      for (int k = 0; k < 8; ++k) {
        float4 a = av[lane + 16 * k];
        float4 w = wv[lane + 16 * k];
        s += a.x * w.x + a.y * w.y + a.z * w.z + a.w * w.w;
      }
      s += __shfl_xor(s, 1); s += __shfl_xor(s, 2); s += __shfl_xor(s, 4); s += __shfl_xor(s, 8);
      if (lane == 0) {
        if (e < 16) dts[row][e] = s;
        else { bcs[row][e - 16] = s; BCbuf[(size_t)(base + row) * 32 + (e - 16)] = s; }
      }
    }
  }
  __syncthreads();
  // dt_proj + softplus -> dlt_s + delt
#pragma unroll
  for (int i = 0; i < 32; ++i) {
    int o = i * 256 + t;
    int row = o >> 9, d = o & 511;
    float s = dtb[d];
#pragma unroll
    for (int r = 0; r < 16; ++r) s += dts[row][r] * dtw[d * 16 + r];
    float sp = (s > 15.f) ? s : log1pf(__expf(s));
    ushort u = f2bf(sp);
    dlt_s[row][d] = u;
    delt[(size_t)(base + row) * 512 + d] = u;
  }
  __syncthreads();
  // scan pass 1 (chunk-local) from LDS: thread owns d = 2t, 2t+1
  {
    int d0 = t * 2;
    float an0[16], an1[16], h0[16], h1[16];
#pragma unroll
    for (int n = 0; n < 16; ++n) {
      an0[n] = anv[n * 512 + d0];
      an1[n] = anv[n * 512 + d0 + 1];
      h0[n] = 0.f; h1[n] = 0.f;
    }
    float sd0 = 0.f, sd1 = 0.f;
#pragma unroll 4
    for (int r = 0; r < LCH; ++r) {
      float dl0 = bf2f(dlt_s[r][d0]);
      float dl1 = bf2f(dlt_s[r][d0 + 1]);
      float dx0 = dl0 * xcs[r][d0];
      float dx1 = dl1 * xcs[r][d0 + 1];
      sd0 += dl0; sd1 += dl1;
#pragma unroll
      for (int n = 0; n < 16; ++n) {
        float bc = bcs[r][n];
        h0[n] = __expf(dl0 * an0[n]) * h0[n] + dx0 * bc;
        h1[n] = __expf(dl1 * an1[n]) * h1[n] + dx1 * bc;
      }
    }
    int chunk = b * GCH + g;
    *reinterpret_cast<float2*>(&sumd[(size_t)chunk * 512 + d0]) = make_float2(sd0, sd1);
#pragma unroll
    for (int n = 0; n < 16; ++n) {
      *reinterpret_cast<float2*>(&Sbuf[((size_t)chunk * 16 + n) * 512 + d0]) = make_float2(h0[n], h1[n]);
    }
  }
}

// ======== kernel 3: chunk combine -> Hinit (P = exp(an*sumd)) ========
__global__ __launch_bounds__(256) void k_comb(const float* __restrict__ sumd,
                                              const float* __restrict__ Sbuf,
                                              const float* __restrict__ anv,
                                              float* __restrict__ Hinit){
  __shared__ float PL[8 * 32];
  __shared__ float SL[8 * 32];
  int bid = blockIdx.x;            // 512 = b(1) n(4) d0(4)
  int b = bid >> 8, n = (bid >> 4) & 15, d0 = (bid & 15) * 32;
  int t = threadIdx.x;
  int j = t >> 5, dl = t & 31;
  int d = d0 + dl;
  float an = anv[n * 512 + d];
  float Pa[16], Sa[16];
  float P = 1.f, S = 0.f;
#pragma unroll
  for (int i = 0; i < 16; ++i) {
    int c = b * GCH + j * 16 + i;
    float sd = sumd[(size_t)c * 512 + d];
    float p = __expf(an * sd);
    float s = Sbuf[((size_t)c * 16 + n) * 512 + d];
    Pa[i] = p; Sa[i] = s;
    S = p * S + s; P *= p;
  }
  PL[j * 32 + dl] = P; SL[j * 32 + dl] = S;
  __syncthreads();
  if (t < 32) {
    float hp = 0.f;
    for (int jj = 0; jj < 8; ++jj) {
      float p = PL[jj * 32 + t], s = SL[jj * 32 + t];
      SL[jj * 32 + t] = hp;
      hp = p * hp + s;
    }
  }
  __syncthreads();
  float h = SL[j * 32 + dl];
#pragma unroll
  for (int i = 0; i < 16; ++i) {
    int c = b * GCH + j * 16 + i;
    Hinit[((size_t)c * 16 + n) * 512 + d] = h;
    h = Pa[i] * h + Sa[i];
  }
}

// ======== kernel 4: scan pass 2 + y + D-skip + gate -> ygb ========
__global__ __launch_bounds__(256) void k_scan2(const ushort* __restrict__ deltab,
                                               const ushort* __restrict__ xcb,
                                               const float* __restrict__ BCbuf,
                                               const float* __restrict__ anv,
                                               const float* __restrict__ Hinit,
                                               const ushort* __restrict__ gb,
                                               const float* __restrict__ Dw,
                                               ushort* __restrict__ ygb){
  __shared__ float bcs[LCH][32];
  int bid = blockIdx.x;            // 512 = b(1) g(7) dh(1)
  int b = bid >> 8;
  int g = (bid >> 1) & 127;
  int dh = bid & 1;
  int t = threadIdx.x;
  int d = dh * 256 + t;
  int base = b * SEQ + g * LCH;
  {
    float2 v = *reinterpret_cast<const float2*>(&BCbuf[(size_t)base * 32 + t * 2]);
    *reinterpret_cast<float2*>(&((float*)bcs)[t * 2]) = v;
  }
  __syncthreads();
  float an[16], h[16];
  size_t hb0 = ((size_t)(b * GCH + g) * 16) * 512 + d;
#pragma unroll
  for (int n = 0; n < 16; ++n) { an[n] = anv[n * 512 + d]; h[n] = Hinit[hb0 + (size_t)n * 512]; }
  float Dd = Dw[d];
  for (int s = 0; s < LCH; ++s) {
    int row = base + s;
    float dl = bf2f(deltab[(size_t)row * 512 + d]);
    float xv = bf2f(xcb[(size_t)row * 512 + d]);
    float dx = dl * xv;
    float y = 0.f;
#pragma unroll
    for (int n = 0; n < 16; ++n) {
      float dA = __expf(dl * an[n]);
      h[n] = dA * h[n] + dx * bcs[s][n];
      y += h[n] * bcs[s][16 + n];
    }
    float zg = bf2f(gb[(size_t)row * 512 + d]);
    ygb[(size_t)row * 512 + d] = f2bf((y + xv * Dd) * zg);
  }
}

// ======== kernel 5: GEMM3 out = residual + yg.Wout^T ========
__global__ __launch_bounds__(256) void k_gemm3(const ushort* __restrict__ A,
                                               const ushort* __restrict__ B,
                                               const float* __restrict__ x,
                                               float* __restrict__ out){
  __shared__ ushort Als[128][72];
  __shared__ ushort Bls[64][72];
  int m0 = blockIdx.x * 128, n0 = blockIdx.y * 64;
  int t = threadIdx.x;
  int w = t >> 6, l = t & 63;
  int wr = w >> 1, wc = w & 1;
  f32x4 acc[4][2] = {};
  int sr = t >> 3, sc = t & 7;
  for (int k0 = 0; k0 < DINNER; k0 += 64) {
#pragma unroll
    for (int p = 0; p < 4; ++p) {
      int r = sr + p * 32;
      *reinterpret_cast<int4*>(&Als[r][sc * 8]) =
        *reinterpret_cast<const int4*>(&A[((size_t)(m0 + r)) * DINNER + k0 + sc * 8]);
    }
#pragma unroll
    for (int p = 0; p < 2; ++p) {
      int r = sr + p * 32;
      *reinterpret_cast<int4*>(&Bls[r][sc * 8]) =
        *reinterpret_cast<const int4*>(&B[((size_t)(n0 + r)) * DINNER + k0 + sc * 8]);
    }
    __syncthreads();
#pragma unroll
    for (int ks = 0; ks < 2; ++ks) {
      s16x8 af[4], bf[2];
      int kk = ks * 32 + 8 * (l >> 4);
#pragma unroll
      for (int i = 0; i < 4; ++i)
        af[i] = *reinterpret_cast<const s16x8*>(&Als[wr * 64 + i * 16 + (l & 15)][kk]);
#pragma unroll
      for (int i = 0; i < 2; ++i)
        bf[i] = *reinterpret_cast<const s16x8*>(&Bls[wc * 32 + i * 16 + (l & 15)][kk]);
#pragma unroll
      for (int mi = 0; mi < 4; ++mi)
#pragma unroll
        for (int ni = 0; ni < 2; ++ni)
          acc[mi][ni] = __builtin_amdgcn_mfma_f32_16x16x32_bf16(af[mi], bf[ni], acc[mi][ni], 0, 0, 0);
    }
    __syncthreads();
  }
  int rq = l >> 4, cc = l & 15;
#pragma unroll
  for (int mi = 0; mi < 4; ++mi)
#pragma unroll
    for (int ni = 0; ni < 2; ++ni) {
      int n = n0 + wc * 32 + ni * 16 + cc;
      int mB = m0 + wr * 64 + mi * 16 + rq * 4;
#pragma unroll
      for (int r2 = 0; r2 < 4; ++r2) {
        int m = mB + r2;
        int b = m >> 11;
        int lb = m & (SEQ - 1);
        size_t addr = ((size_t)(b * DMODEL + n)) * SEQ + lb;
        out[addr] = acc[mi][ni][r2] + x[addr];
      }
    }
}

extern "C" void kernel_launch(void* const* d_in, const int* in_sizes, int n_in,
                              void* d_out, int out_size, void* d_ws, size_t ws_size,
                              hipStream_t stream) {
  const float* x          = (const float*)d_in[0];
  const float* norm_w     = (const float*)d_in[1];
  const float* in_proj_w  = (const float*)d_in[2];
  const float* conv_w     = (const float*)d_in[3];
  const float* conv_b     = (const float*)d_in[4];
  const float* x_proj_w   = (const float*)d_in[5];
  const float* dt_proj_w  = (const float*)d_in[6];
  const float* dt_proj_b  = (const float*)d_in[7];
  const float* A_log      = (const float*)d_in[8];
  const float* Dw         = (const float*)d_in[9];
  const float* out_proj_w = (const float*)d_in[10];
  float* out = (float*)d_out;
  float* ws  = (float*)d_ws;

  float* BCbuf = ws + OFF_BC;
  float* Sbuf  = ws + OFF_S;
  float* Hinit = ws + OFF_H;
  float* anv   = ws + OFF_ANV;
  float* sumd  = ws + OFF_SD;
  ushort* ub   = (ushort*)(ws + OFF_US);
  ushort* wob  = ub + UOFF_WOB;
  ushort* xzb  = ub + UOFF_XZ;
  ushort* xcb  = ub + UOFF_XC;
  ushort* gb   = ub + UOFF_G;
  ushort* delt = ub + UOFF_DL;
  ushort* ygb  = ub + UOFF_YG;

  k_g1   <<<256,          256, 0, stream>>>(x, norm_w, in_proj_w, out_proj_w, A_log, wob, anv, xzb);
  k_cs1  <<<256,          256, 0, stream>>>(xzb, conv_w, conv_b, x_proj_w, dt_proj_w, dt_proj_b,
                                            anv, xcb, gb, BCbuf, delt, Sbuf, sumd);
  k_comb <<<512,          256, 0, stream>>>(sumd, Sbuf, anv, Hinit);
  k_scan2<<<512,          256, 0, stream>>>(delt, xcb, BCbuf, anv, Hinit, gb, Dw, ygb);
  k_gemm3<<<dim3(32, 4),  256, 0, stream>>>(ygb, wob, x, out);
}

// Round 9
// 93.662 us; speedup vs baseline: 8.2397x; 1.0781x over previous
//
#include <hip/hip_runtime.h>
#include <hip/hip_bf16.h>
#include <math.h>

#define BATCH  2
#define SEQ    2048
#define DMODEL 256
#define DSTATE 16
#define DINNER 512
#define RTOT   4096
#define GCH    128
#define LCH    16
#define NW2    (DMODEL*DINNER)     // 131072

typedef float f32x4 __attribute__((ext_vector_type(4)));
typedef short s16x8 __attribute__((ext_vector_type(8)));

__device__ __forceinline__ float silu_f(float v){ return v / (1.f + __expf(-v)); }
__device__ __forceinline__ ushort f2bf(float f){
  __hip_bfloat16 h = __float2bfloat16(f);
  return *reinterpret_cast<ushort*>(&h);
}
__device__ __forceinline__ float bf2f(ushort u){
  union { unsigned int i; float f; } c; c.i = ((unsigned int)u) << 16; return c.f;
}

// ---- workspace layout (float offsets) ----
#define OFF_BC   0
#define OFF_S    (OFF_BC + RTOT*32)          // S: 2*128*16*512
#define OFF_H    (OFF_S + 2*GCH*16*512)      // Hinit
#define OFF_ANV  (OFF_H + 2*GCH*16*512)      // 16*512
#define OFF_SD   (OFF_ANV + 16*512)          // sumd: 2*128*512
#define OFF_US   (OFF_SD + 2*GCH*512)
#define UOFF_WOB ((size_t)0)
#define UOFF_XZ  (UOFF_WOB + (size_t)NW2)
#define UOFF_XC  (UOFF_XZ + (size_t)RTOT*1024)
#define UOFF_G   (UOFF_XC + (size_t)RTOT*512)
#define UOFF_DL  (UOFF_G  + (size_t)RTOT*512)
#define UOFF_YG  (UOFF_DL + (size_t)RTOT*512)

// ======== kernel 1: RMSNorm-into-LDS + B-panel cvt + GEMM1 (128x128) + wob/anv tails ========
__global__ __launch_bounds__(256) void k_g1(const float* __restrict__ x,
                                            const float* __restrict__ norm_w,
                                            const float* __restrict__ w_in,
                                            const float* __restrict__ w_out,
                                            const float* __restrict__ A_log,
                                            ushort* __restrict__ wob,
                                            float* __restrict__ anv,
                                            ushort* __restrict__ xzb){
  __shared__ ushort As[128][264];
  __shared__ ushort Bls[128][264];
  __shared__ float red[4][64];
  int bid = blockIdx.x;
  int t = threadIdx.x;
  // tails: out_proj cvt (512 elems/block) + A-table (blocks 0..31)
  {
    int base = bid * 512 + (t & 127) * 4;
    if (t < 128) {
      float4 v = *reinterpret_cast<const float4*>(&w_out[base]);
      ushort4 o; o.x = f2bf(v.x); o.y = f2bf(v.y); o.z = f2bf(v.z); o.w = f2bf(v.w);
      *reinterpret_cast<ushort4*>(&wob[base]) = o;
    }
    if (bid < 32) {
      int e = bid * 256 + t;           // e = n*512 + d
      int n = e >> 9, d = e & 511;
      anv[e] = -__expf(A_log[d * 16 + n]);
    }
  }
  int mB = bid >> 3, nB = bid & 7;
  int m0 = mB * 128, n0 = nB * 128;
  int b = mB >> 4;
  int l0 = (mB & 15) << 7;
  const float* xb = x + (size_t)b * DMODEL * SEQ;
  int ll = t & 63, cq = t >> 6;
  // ---- RMSNorm into As (two 64-row halves) ----
  for (int half = 0; half < 2; ++half) {
    int l = l0 + half * 64 + ll;
    float ss = 0.f;
    for (int it = 0; it < 64; ++it) {
      int c = cq * 64 + it;
      float v = xb[(size_t)c * SEQ + l];
      ss += v * v;
    }
    red[cq][ll] = ss;
    __syncthreads();
    float s = red[0][ll] + red[1][ll] + red[2][ll] + red[3][ll];
    float r = rsqrtf(s * (1.f / DMODEL) + 1e-5f);
    for (int it = 0; it < 64; ++it) {
      int c = cq * 64 + it;
      float v = xb[(size_t)c * SEQ + l];
      As[half * 64 + ll][c] = f2bf(v * r * norm_w[c]);
    }
    __syncthreads();
  }
  // ---- B-panel cvt into Bls ----
  {
    int r = t >> 1, ch = t & 1;
    const float* wr_ = &w_in[(size_t)(n0 + r) * DMODEL + ch * 128];
#pragma unroll
    for (int j = 0; j < 32; ++j) {
      float4 v = *reinterpret_cast<const float4*>(&wr_[j * 4]);
      ushort4 o; o.x = f2bf(v.x); o.y = f2bf(v.y); o.z = f2bf(v.z); o.w = f2bf(v.w);
      *reinterpret_cast<ushort4*>(&Bls[r][ch * 128 + j * 4]) = o;
    }
  }
  __syncthreads();
  // ---- GEMM from LDS (K=256, no restaging) ----
  int w = t >> 6, l = t & 63;
  int wr = w >> 1, wc = w & 1;
  f32x4 acc[4][4] = {};
#pragma unroll
  for (int ks = 0; ks < 8; ++ks) {
    int kk = ks * 32 + 8 * (l >> 4);
    s16x8 af[4], bf[4];
#pragma unroll
    for (int i = 0; i < 4; ++i) {
      af[i] = *reinterpret_cast<const s16x8*>(&As[wr * 64 + i * 16 + (l & 15)][kk]);
      bf[i] = *reinterpret_cast<const s16x8*>(&Bls[wc * 64 + i * 16 + (l & 15)][kk]);
    }
#pragma unroll
    for (int mi = 0; mi < 4; ++mi)
#pragma unroll
      for (int ni = 0; ni < 4; ++ni)
        acc[mi][ni] = __builtin_amdgcn_mfma_f32_16x16x32_bf16(af[mi], bf[ni], acc[mi][ni], 0, 0, 0);
  }
  int rq = l >> 4, cc = l & 15;
#pragma unroll
  for (int mi = 0; mi < 4; ++mi)
#pragma unroll
    for (int ni = 0; ni < 4; ++ni) {
      int n = n0 + wc * 64 + ni * 16 + cc;
      int mB2 = m0 + wr * 64 + mi * 16 + rq * 4;
#pragma unroll
      for (int r2 = 0; r2 < 4; ++r2)
        xzb[(size_t)(mB2 + r2) * 1024 + n] = f2bf(acc[mi][ni][r2]);
    }
}

// ======== kernel 2: conv+SiLU + gate + x_proj + dt_proj (1024 blocks x 4 rows) ========
__global__ __launch_bounds__(256) void k_cxp(const ushort* __restrict__ xzb,
                                             const float* __restrict__ conv_w,
                                             const float* __restrict__ conv_b,
                                             const float* __restrict__ xpw,   // [48][512]
                                             const float* __restrict__ dtw,   // [512][16]
                                             const float* __restrict__ dtb,
                                             ushort* __restrict__ xcb,
                                             ushort* __restrict__ gb,
                                             float* __restrict__ BCbuf,
                                             ushort* __restrict__ deltab){
  __shared__ float xcs[4][520];
  __shared__ float dts[4][16];
  int t = threadIdx.x;
  int r0 = blockIdx.x * 4;
  int b = r0 >> 11;
  int l0 = r0 & (SEQ - 1);
  int rr = t >> 6;
  int dbase = (t & 63) * 8;
  int l = l0 + rr;
  size_t rowg = (size_t)b * SEQ + l;
  float acc[8];
  float4 cw[8];
#pragma unroll
  for (int dd = 0; dd < 8; ++dd) {
    cw[dd] = *reinterpret_cast<const float4*>(&conv_w[(dbase + dd) * 4]);
    acc[dd] = conv_b[dbase + dd];
  }
#pragma unroll
  for (int k = 0; k < 4; ++k) {
    int ls = l - 3 + k;
    if (ls >= 0) {
      ushort u[8];
      *reinterpret_cast<int4*>(u) =
        *reinterpret_cast<const int4*>(&xzb[((size_t)b * SEQ + ls) * 1024 + dbase]);
#pragma unroll
      for (int dd = 0; dd < 8; ++dd) {
        float wv = (k == 0) ? cw[dd].x : (k == 1) ? cw[dd].y : (k == 2) ? cw[dd].z : cw[dd].w;
        acc[dd] += bf2f(u[dd]) * wv;
      }
    }
  }
  {
    ushort uz[8], outx[8], outg[8];
    *reinterpret_cast<int4*>(uz) =
      *reinterpret_cast<const int4*>(&xzb[rowg * 1024 + 512 + dbase]);
#pragma unroll
    for (int dd = 0; dd < 8; ++dd) {
      float v = silu_f(acc[dd]);
      xcs[rr][dbase + dd] = v;
      outx[dd] = f2bf(v);
      outg[dd] = f2bf(silu_f(bf2f(uz[dd])));
    }
    *reinterpret_cast<int4*>(&xcb[rowg * 512 + dbase]) = *reinterpret_cast<int4*>(outx);
    *reinterpret_cast<int4*>(&gb [rowg * 512 + dbase]) = *reinterpret_cast<int4*>(outg);
  }
  __syncthreads();
  // x_proj: 192 outputs (4 rows x 48), 16-lane K-split + shfl reduce
  int lane = t & 15;
  int grp = t >> 4;
#pragma unroll
  for (int p = 0; p < 12; ++p) {
    int o = p * 16 + grp;
    int row = o / 48, e = o % 48;
    const float4* wv = reinterpret_cast<const float4*>(&xpw[e * 512]);
    const float4* av = reinterpret_cast<const float4*>(&xcs[row][0]);
    float s = 0.f;
#pragma unroll
    for (int k = 0; k < 8; ++k) {
      float4 a = av[lane + 16 * k];
      float4 w = wv[lane + 16 * k];
      s += a.x * w.x + a.y * w.y + a.z * w.z + a.w * w.w;
    }
    s += __shfl_xor(s, 1); s += __shfl_xor(s, 2); s += __shfl_xor(s, 4); s += __shfl_xor(s, 8);
    if (lane == 0) {
      if (e < 16) dts[row][e] = s;
      else BCbuf[(size_t)(r0 + row) * 32 + (e - 16)] = s;
    }
  }
  __syncthreads();
  // dt_proj + softplus -> delta bf16
#pragma unroll
  for (int i = 0; i < 8; ++i) {
    int o = i * 256 + t;
    int row = o >> 9, d = o & 511;
    float s = dtb[d];
#pragma unroll
    for (int r = 0; r < 16; ++r) s += dts[row][r] * dtw[d * 16 + r];
    float sp = (s > 15.f) ? s : log1pf(__expf(s));
    deltab[(size_t)(r0 + row) * 512 + d] = f2bf(sp);
  }
}

// ======== kernel 3: scan pass 1 -> Sbuf, sumd (512 blocks) ========
__global__ __launch_bounds__(256) void k_scan1(const ushort* __restrict__ deltab,
                                               const ushort* __restrict__ xcb,
                                               const float* __restrict__ BCbuf,
                                               const float* __restrict__ anv,
                                               float* __restrict__ Sbuf,
                                               float* __restrict__ sumd){
  __shared__ float bcs[LCH][32];
  int bid = blockIdx.x;            // 512 = b(1) g(7) dh(1)
  int b = bid >> 8;
  int g = (bid >> 1) & 127;
  int dh = bid & 1;
  int t = threadIdx.x;
  int d = dh * 256 + t;
  int base = b * SEQ + g * LCH;
  {
    float2 v = *reinterpret_cast<const float2*>(&BCbuf[(size_t)base * 32 + t * 2]);
    *reinterpret_cast<float2*>(&((float*)bcs)[t * 2]) = v;
  }
  __syncthreads();
  float an[16], h[16];
#pragma unroll
  for (int n = 0; n < 16; ++n) { an[n] = anv[n * 512 + d]; h[n] = 0.f; }
  float sd = 0.f;
  for (int s = 0; s < LCH; ++s) {
    int row = base + s;
    float dl = bf2f(deltab[(size_t)row * 512 + d]);
    float xv = bf2f(xcb[(size_t)row * 512 + d]);
    float dx = dl * xv;
    sd += dl;
#pragma unroll
    for (int n = 0; n < 16; ++n) {
      float dA = __expf(dl * an[n]);
      h[n] = dA * h[n] + dx * bcs[s][n];
    }
  }
  int chunk = b * GCH + g;
  sumd[(size_t)chunk * 512 + d] = sd;
#pragma unroll
  for (int n = 0; n < 16; ++n)
    Sbuf[((size_t)chunk * 16 + n) * 512 + d] = h[n];
}

// ======== kernel 4: chunk combine -> Hinit (P = exp(an*sumd)) ========
__global__ __launch_bounds__(256) void k_comb(const float* __restrict__ sumd,
                                              const float* __restrict__ Sbuf,
                                              const float* __restrict__ anv,
                                              float* __restrict__ Hinit){
  __shared__ float PL[8 * 32];
  __shared__ float SL[8 * 32];
  int bid = blockIdx.x;            // 512 = b(1) n(4) d0(4)
  int b = bid >> 8, n = (bid >> 4) & 15, d0 = (bid & 15) * 32;
  int t = threadIdx.x;
  int j = t >> 5, dl = t & 31;
  int d = d0 + dl;
  float an = anv[n * 512 + d];
  float Pa[16], Sa[16];
  float P = 1.f, S = 0.f;
#pragma unroll
  for (int i = 0; i < 16; ++i) {
    int c = b * GCH + j * 16 + i;
    float sd = sumd[(size_t)c * 512 + d];
    float p = __expf(an * sd);
    float s = Sbuf[((size_t)c * 16 + n) * 512 + d];
    Pa[i] = p; Sa[i] = s;
    S = p * S + s; P *= p;
  }
  PL[j * 32 + dl] = P; SL[j * 32 + dl] = S;
  __syncthreads();
  if (t < 32) {
    float hp = 0.f;
    for (int jj = 0; jj < 8; ++jj) {
      float p = PL[jj * 32 + t], s = SL[jj * 32 + t];
      SL[jj * 32 + t] = hp;
      hp = p * hp + s;
    }
  }
  __syncthreads();
  float h = SL[j * 32 + dl];
#pragma unroll
  for (int i = 0; i < 16; ++i) {
    int c = b * GCH + j * 16 + i;
    Hinit[((size_t)c * 16 + n) * 512 + d] = h;
    h = Pa[i] * h + Sa[i];
  }
}

// ======== kernel 5: scan pass 2 + y + D-skip + gate -> ygb ========
__global__ __launch_bounds__(256) void k_scan2(const ushort* __restrict__ deltab,
                                               const ushort* __restrict__ xcb,
                                               const float* __restrict__ BCbuf,
                                               const float* __restrict__ anv,
                                               const float* __restrict__ Hinit,
                                               const ushort* __restrict__ gb,
                                               const float* __restrict__ Dw,
                                               ushort* __restrict__ ygb){
  __shared__ float bcs[LCH][32];
  int bid = blockIdx.x;            // 512 = b(1) g(7) dh(1)
  int b = bid >> 8;
  int g = (bid >> 1) & 127;
  int dh = bid & 1;
  int t = threadIdx.x;
  int d = dh * 256 + t;
  int base = b * SEQ + g * LCH;
  {
    float2 v = *reinterpret_cast<const float2*>(&BCbuf[(size_t)base * 32 + t * 2]);
    *reinterpret_cast<float2*>(&((float*)bcs)[t * 2]) = v;
  }
  __syncthreads();
  float an[16], h[16];
  size_t hb0 = ((size_t)(b * GCH + g) * 16) * 512 + d;
#pragma unroll
  for (int n = 0; n < 16; ++n) { an[n] = anv[n * 512 + d]; h[n] = Hinit[hb0 + (size_t)n * 512]; }
  float Dd = Dw[d];
  for (int s = 0; s < LCH; ++s) {
    int row = base + s;
    float dl = bf2f(deltab[(size_t)row * 512 + d]);
    float xv = bf2f(xcb[(size_t)row * 512 + d]);
    float dx = dl * xv;
    float y = 0.f;
#pragma unroll
    for (int n = 0; n < 16; ++n) {
      float dA = __expf(dl * an[n]);
      h[n] = dA * h[n] + dx * bcs[s][n];
      y += h[n] * bcs[s][16 + n];
    }
    float zg = bf2f(gb[(size_t)row * 512 + d]);
    ygb[(size_t)row * 512 + d] = f2bf((y + xv * Dd) * zg);
  }
}

// ======== kernel 6: GEMM3 out = residual + yg.Wout^T ========
__global__ __launch_bounds__(256) void k_gemm3(const ushort* __restrict__ A,
                                               const ushort* __restrict__ B,
                                               const float* __restrict__ x,
                                               float* __restrict__ out){
  __shared__ ushort Als[128][72];
  __shared__ ushort Bls[64][72];
  int m0 = blockIdx.x * 128, n0 = blockIdx.y * 64;
  int t = threadIdx.x;
  int w = t >> 6, l = t & 63;
  int wr = w >> 1, wc = w & 1;
  f32x4 acc[4][2] = {};
  int sr = t >> 3, sc = t & 7;
  for (int k0 = 0; k0 < DINNER; k0 += 64) {
#pragma unroll
    for (int p = 0; p < 4; ++p) {
      int r = sr + p * 32;
      *reinterpret_cast<int4*>(&Als[r][sc * 8]) =
        *reinterpret_cast<const int4*>(&A[((size_t)(m0 + r)) * DINNER + k0 + sc * 8]);
    }
#pragma unroll
    for (int p = 0; p < 2; ++p) {
      int r = sr + p * 32;
      *reinterpret_cast<int4*>(&Bls[r][sc * 8]) =
        *reinterpret_cast<const int4*>(&B[((size_t)(n0 + r)) * DINNER + k0 + sc * 8]);
    }
    __syncthreads();
#pragma unroll
    for (int ks = 0; ks < 2; ++ks) {
      s16x8 af[4], bf[2];
      int kk = ks * 32 + 8 * (l >> 4);
#pragma unroll
      for (int i = 0; i < 4; ++i)
        af[i] = *reinterpret_cast<const s16x8*>(&Als[wr * 64 + i * 16 + (l & 15)][kk]);
#pragma unroll
      for (int i = 0; i < 2; ++i)
        bf[i] = *reinterpret_cast<const s16x8*>(&Bls[wc * 32 + i * 16 + (l & 15)][kk]);
#pragma unroll
      for (int mi = 0; mi < 4; ++mi)
#pragma unroll
        for (int ni = 0; ni < 2; ++ni)
          acc[mi][ni] = __builtin_amdgcn_mfma_f32_16x16x32_bf16(af[mi], bf[ni], acc[mi][ni], 0, 0, 0);
    }
    __syncthreads();
  }
  int rq = l >> 4, cc = l & 15;
#pragma unroll
  for (int mi = 0; mi < 4; ++mi)
#pragma unroll
    for (int ni = 0; ni < 2; ++ni) {
      int n = n0 + wc * 32 + ni * 16 + cc;
      int mB = m0 + wr * 64 + mi * 16 + rq * 4;
#pragma unroll
      for (int r2 = 0; r2 < 4; ++r2) {
        int m = mB + r2;
        int b = m >> 11;
        int lb = m & (SEQ - 1);
        size_t addr = ((size_t)(b * DMODEL + n)) * SEQ + lb;
        out[addr] = acc[mi][ni][r2] + x[addr];
      }
    }
}

extern "C" void kernel_launch(void* const* d_in, const int* in_sizes, int n_in,
                              void* d_out, int out_size, void* d_ws, size_t ws_size,
                              hipStream_t stream) {
  const float* x          = (const float*)d_in[0];
  const float* norm_w     = (const float*)d_in[1];
  const float* in_proj_w  = (const float*)d_in[2];
  const float* conv_w     = (const float*)d_in[3];
  const float* conv_b     = (const float*)d_in[4];
  const float* x_proj_w   = (const float*)d_in[5];
  const float* dt_proj_w  = (const float*)d_in[6];
  const float* dt_proj_b  = (const float*)d_in[7];
  const float* A_log      = (const float*)d_in[8];
  const float* Dw         = (const float*)d_in[9];
  const float* out_proj_w = (const float*)d_in[10];
  float* out = (float*)d_out;
  float* ws  = (float*)d_ws;

  float* BCbuf = ws + OFF_BC;
  float* Sbuf  = ws + OFF_S;
  float* Hinit = ws + OFF_H;
  float* anv   = ws + OFF_ANV;
  float* sumd  = ws + OFF_SD;
  ushort* ub   = (ushort*)(ws + OFF_US);
  ushort* wob  = ub + UOFF_WOB;
  ushort* xzb  = ub + UOFF_XZ;
  ushort* xcb  = ub + UOFF_XC;
  ushort* gb   = ub + UOFF_G;
  ushort* delt = ub + UOFF_DL;
  ushort* ygb  = ub + UOFF_YG;

  k_g1   <<<256,          256, 0, stream>>>(x, norm_w, in_proj_w, out_proj_w, A_log, wob, anv, xzb);
  k_cxp  <<<1024,         256, 0, stream>>>(xzb, conv_w, conv_b, x_proj_w, dt_proj_w, dt_proj_b,
                                            xcb, gb, BCbuf, delt);
  k_scan1<<<512,          256, 0, stream>>>(delt, xcb, BCbuf, anv, Sbuf, sumd);
  k_comb <<<512,          256, 0, stream>>>(sumd, Sbuf, anv, Hinit);
  k_scan2<<<512,          256, 0, stream>>>(delt, xcb, BCbuf, anv, Hinit, gb, Dw, ygb);
  k_gemm3<<<dim3(32, 4),  256, 0, stream>>>(ygb, wob, x, out);
}